// Round 9
// baseline (6444.836 us; speedup 1.0000x reference)
//
#include <hip/hip_runtime.h>

// SimpleLSTM B=64, T=2048, H=512. Round 9 = R6 (proven) + two changes.
// HANG RULE (R4..R8 triangulation): any poll that L1 can serve spins forever
// (sc0 loads are L1-cacheable; fetch_add(p,0) gets strength-reduced to a plain
// load). Polls must be TCC ops the compiler can't touch -> inline-asm
// global_atomic_add (add-0, sc0 returns old value). R6's bulk sc0 A-loads are
// safe only because 64KB/step capacity-evicts the 32KB L1 (4-step reuse
// distance) — deterministic for data, fatal for single hot poll lines.
// Change 1: y via private per-block partials + yred kernel (R6's 32-way
//   same-dword MALL atomicAdd ack sat inside the pre-B3 vmcnt(0) drain).
// Change 2: sync = one sum counter per group in the XCD's L2 via asm atomics
//   (signal +1 after B3; tid0 polls add-0 >= 32t). DEPTH-4 WAR-safe: writer
//   at iter t+3 needs done>=32t+96 but slowest-at-t bounds sum<=32t+93.
// Probe gates the asm-atomic mechanism per group; SLOW fallback = agent scope.

#define TT 2048
#define BB 64
#define HH 512
#define GB 8            // batches per group
#define NBLK 32         // blocks per group
#define DEPTH 4
#define PLANE (GB * HH) // 4096 bf16 per plane-slot (8 KB)
#define Y_OFF 0
#define HN_OFF (BB * TT)
#define CN_OFF (BB * TT + BB * HH)
#define RING_OFF 16384  // bytes into ws
#define PART_OFF (16384 + 524288)
#define PART_BYTES (8 * NBLK * GB * TT * 4)  // 16 MB

typedef short short8 __attribute__((ext_vector_type(8)));
typedef float f32x4  __attribute__((ext_vector_type(4)));

__device__ __forceinline__ unsigned f2bf(float f) {  // RNE fp32->bf16 bits
    unsigned u = __float_as_uint(f);
    return (u + 0x7fffu + ((u >> 16) & 1u)) >> 16;
}
__device__ __forceinline__ float bf2f(unsigned h) { return __uint_as_float(h << 16); }

// ---- relaxed agent-scope (sc1/MALL) primitives — R3/R6-proven -------------
__device__ __forceinline__ unsigned ld_agent(const unsigned* p) {
    return __hip_atomic_load(p, __ATOMIC_RELAXED, __HIP_MEMORY_SCOPE_AGENT);
}
__device__ __forceinline__ void st_agent(unsigned* p, unsigned v) {
    __hip_atomic_store(p, v, __ATOMIC_RELAXED, __HIP_MEMORY_SCOPE_AGENT);
}
__device__ __forceinline__ unsigned add_agent(unsigned* p, unsigned v) {
    return __hip_atomic_fetch_add(p, v, __ATOMIC_RELAXED, __HIP_MEMORY_SCOPE_AGENT);
}
__device__ __forceinline__ short8 ld_sc1_b128(const unsigned short* p) {
    unsigned long long q0 = __hip_atomic_load((const unsigned long long*)p,
                                              __ATOMIC_RELAXED, __HIP_MEMORY_SCOPE_AGENT);
    unsigned long long q1 = __hip_atomic_load((const unsigned long long*)(p + 4),
                                              __ATOMIC_RELAXED, __HIP_MEMORY_SCOPE_AGENT);
    union { unsigned long long q[2]; short8 s; } u;
    u.q[0] = q0; u.q[1] = q1;
    return u.s;
}

// ---- XCD-local TCC atomics (asm: compiler cannot reduce them to loads) ----
__device__ __forceinline__ unsigned l2_poll_rmw(unsigned* p) {  // returns old
    unsigned ret;
    asm volatile("global_atomic_add %0, %1, %2, off sc0\n\t"
                 "s_waitcnt vmcnt(0)"
                 : "=&v"(ret) : "v"(p), "v"(0u) : "memory");
    return ret;
}
__device__ __forceinline__ void l2_signal_add(unsigned* p, unsigned v) {
    asm volatile("global_atomic_add %0, %1, off" :: "v"(p), "v"(v) : "memory");
}

// ---- sc0 bulk loads (fresh by L1 capacity eviction — R6-proven) -----------
__device__ __forceinline__ void ld_sc0_8x128(const void* pa, const void* pb,
                                             short8* A, short8* B) {
    asm volatile(
        "global_load_dwordx4 %0, %[pa], off sc0\n\t"
        "global_load_dwordx4 %1, %[pa], off offset:64 sc0\n\t"
        "global_load_dwordx4 %2, %[pa], off offset:128 sc0\n\t"
        "global_load_dwordx4 %3, %[pa], off offset:192 sc0\n\t"
        "global_load_dwordx4 %4, %[pb], off sc0\n\t"
        "global_load_dwordx4 %5, %[pb], off offset:64 sc0\n\t"
        "global_load_dwordx4 %6, %[pb], off offset:128 sc0\n\t"
        "global_load_dwordx4 %7, %[pb], off offset:192 sc0\n\t"
        "s_waitcnt vmcnt(0)"
        : "=&v"(A[0]), "=&v"(A[1]), "=&v"(A[2]), "=&v"(A[3]),
          "=&v"(B[0]), "=&v"(B[1]), "=&v"(B[2]), "=&v"(B[3])
        : [pa] "v"(pa), [pb] "v"(pb)
        : "memory");
}
__device__ __forceinline__ uint4 ld_sc0_probe(const void* p) {
    uint4 d;
    asm volatile("global_load_dwordx4 %0, %1, off sc0\n\ts_waitcnt vmcnt(0)"
                 : "=&v"(d) : "v"(p) : "memory");
    return d;
}

#define GSP(w, tl, r, c) gsp[((((w) * 4 + (tl)) * 16 + (r)) * 20) + (c)]

template <bool FAST>
__device__ __noinline__ void run_loop(
    const float* __restrict__ x, const float* __restrict__ Whh,
    const float* __restrict__ Wih, const float* __restrict__ bih,
    const float* __restrict__ bhh, const float* __restrict__ Wfc,
    const float* __restrict__ bfc, float* __restrict__ out,
    unsigned short* __restrict__ hb, unsigned* __restrict__ done,
    float* __restrict__ party,  // per-block y partials, or nullptr
    const int grp, const int ut, float* gsp)
{
    const int tid  = threadIdx.x;
    const int wid  = tid >> 6;          // wave 0..3 -> K-slice wid*128..+128
    const int lane = tid & 63;
    const int quad = lane >> 4;
    const int l16  = lane & 15;

    // ---- persistent W fragments (hi/lo split); tile tl = gate, 16 units ----
    short8 whi[4][4], wlo[4][4];
#pragma unroll
    for (int tl = 0; tl < 4; ++tl) {
        const int grow  = tl * HH + ut * 16 + l16;   // row = gate*512 + unit
        const float* wr = Whh + grow * HH + wid * 128 + quad * 8;
#pragma unroll
        for (int ki = 0; ki < 4; ++ki) {
            const float* wp = wr + ki * 32;
            short8 h8, l8;
#pragma unroll
            for (int j = 0; j < 8; ++j) {
                const float f = wp[j];
                const unsigned hi = f2bf(f);
                h8[j] = (short)hi;
                l8[j] = (short)f2bf(f - bf2f(hi));
            }
            whi[tl][ki] = h8;
            wlo[tl][ki] = l8;
        }
    }

    // ---- epilogue role (tid < 128): batch b2, unit u ----
    const int b2    = (tid >> 4) & 7;
    const int u     = tid & 15;
    const int bglob = grp * GB + b2;
    const int ug    = ut * 16 + u;
    float wih4[4], bia4[4];
#pragma unroll
    for (int gi = 0; gi < 4; ++gi) {
        const int grow = gi * HH + ug;
        wih4[gi] = Wih[grow];
        bia4[gi] = bih[grow] + bhh[grow];
    }
    const float wfc  = Wfc[ug];
    const float bfcv = bfc[0];
    float c = 0.0f;

    const int base_hi = grp * 2 * DEPTH;
    const int base_lo = base_hi + DEPTH;
    unsigned* hb32 = (unsigned*)hb;

    for (int t = 0; t < TT; ++t) {
        // ---- B1: sum-counter min-barrier (32 block-adds per step) ----
        if (tid == 0) {
            const unsigned tgt = (unsigned)t * 32u;
            if constexpr (FAST) {
                while (l2_poll_rmw(done) < tgt) {}   // TCC RMW: L1-proof
            } else {
                while (ld_agent(done) < tgt) __builtin_amdgcn_s_sleep(1);
            }
        }
        __syncthreads();

        const float xv = x[bglob * TT + t];

        // ---- A = H[8(dup16) x 512] from ring slot t&3, this wave's K-slice ----
        const unsigned short* Ah =
            hb + (base_hi + (t & 3)) * PLANE + (l16 & 7) * HH + wid * 128 + quad * 8;
        const unsigned short* Al =
            hb + (base_lo + (t & 3)) * PLANE + (l16 & 7) * HH + wid * 128 + quad * 8;
        short8 ah[4], al[4];
        if constexpr (FAST) {
            ld_sc0_8x128(Ah, Al, ah, al);   // XCD-L2; L1 capacity-evicted (R6)
        } else {
#pragma unroll
            for (int ki = 0; ki < 4; ++ki) {
                ah[ki] = ld_sc1_b128(Ah + ki * 32);
                al[ki] = ld_sc1_b128(Al + ki * 32);
            }
        }

        f32x4 acc[4] = {{0.f,0.f,0.f,0.f},{0.f,0.f,0.f,0.f},
                        {0.f,0.f,0.f,0.f},{0.f,0.f,0.f,0.f}};
#pragma unroll
        for (int ki = 0; ki < 4; ++ki) {
#pragma unroll
            for (int tl = 0; tl < 4; ++tl)
                acc[tl] = __builtin_amdgcn_mfma_f32_16x16x32_bf16(ah[ki], whi[tl][ki], acc[tl], 0, 0, 0);
#pragma unroll
            for (int tl = 0; tl < 4; ++tl)
                acc[tl] = __builtin_amdgcn_mfma_f32_16x16x32_bf16(al[ki], whi[tl][ki], acc[tl], 0, 0, 0);
#pragma unroll
            for (int tl = 0; tl < 4; ++tl)
                acc[tl] = __builtin_amdgcn_mfma_f32_16x16x32_bf16(ah[ki], wlo[tl][ki], acc[tl], 0, 0, 0);
        }
        // D: col=lane&15 (unit), row=quad*4+reg (batch; rows 8..15 are dups)
#pragma unroll
        for (int tl = 0; tl < 4; ++tl)
#pragma unroll
            for (int r = 0; r < 4; ++r)
                GSP(wid, tl, quad * 4 + r, l16) = acc[tl][r];
        __syncthreads();  // B2

        if (tid < 128) {
            float pre[4];
#pragma unroll
            for (int gi = 0; gi < 4; ++gi) {
                float s = 0.f;
#pragma unroll
                for (int w = 0; w < 4; ++w) s += GSP(w, gi, b2, u);
                pre[gi] = fmaf(xv, wih4[gi], bia4[gi]) + s;
            }
            const float ig = 1.f / (1.f + __expf(-pre[0]));
            const float fg = 1.f / (1.f + __expf(-pre[1]));
            const float gg = 2.f / (1.f + __expf(-2.f * pre[2])) - 1.f;
            const float og = 1.f / (1.f + __expf(-pre[3]));
            c = fmaf(fg, c, ig * gg);
            const float tc = 2.f / (1.f + __expf(-2.f * c)) - 1.f;
            const float h  = og * tc;

            // ---- h -> ring slot (t+1)&3, hi/lo planes, paired dword stores ----
            const unsigned hh = f2bf(h);
            const unsigned hl = f2bf(h - bf2f(hh));
            const unsigned packed = hh | (hl << 16);
            const unsigned part = (unsigned)__shfl_xor((int)packed, 1, 64);
            if ((u & 1) == 0) {
                const unsigned sH = __builtin_amdgcn_perm(part, packed, 0x05040100u);
                const unsigned sL = __builtin_amdgcn_perm(part, packed, 0x07060302u);
                const int slot    = (t + 1) & 3;
                const int pairidx = (b2 * HH + ug) >> 1;
                const int scope   = FAST ? __HIP_MEMORY_SCOPE_WORKGROUP
                                         : __HIP_MEMORY_SCOPE_AGENT;
                __hip_atomic_store(hb32 + (base_hi + slot) * (PLANE / 2) + pairidx, sH,
                                   __ATOMIC_RELAXED, scope);
                __hip_atomic_store(hb32 + (base_lo + slot) * (PLANE / 2) + pairidx, sL,
                                   __ATOMIC_RELAXED, scope);
            }

            // ---- y partial: private line, no contention, off the drain path ----
            float yp = h * wfc;
            yp += __shfl_down(yp, 8, 16);
            yp += __shfl_down(yp, 4, 16);
            yp += __shfl_down(yp, 2, 16);
            yp += __shfl_down(yp, 1, 16);
            if (u == 0) {
                if (party) {
                    party[((grp * NBLK + ut) * GB + b2) * TT + t] = yp;
                } else {
                    if (ut == 0) yp += bfcv;
                    atomicAdd(out + Y_OFF + bglob * TT + t, yp);  // fallback
                }
            }
            if (t == TT - 1) {
                out[HN_OFF + bglob * HH + ug] = h;
                out[CN_OFF + bglob * HH + ug] = c;
            }
        }
        // B3: compiler emits s_waitcnt vmcnt(0) before s_barrier -> all of
        // this block's h-stores are committed to L2 before the signal below.
        __syncthreads();
        if (tid == 0) {
            if constexpr (FAST) l2_signal_add(done, 1u);  // XCD-L2 TCC atomic
            else                add_agent(done, 1u);      // MALL
        }
    }
}

__global__ __launch_bounds__(256, 1)
void lstm_xcd(const float* __restrict__ x, const float* __restrict__ Wih,
              const float* __restrict__ Whh, const float* __restrict__ bih,
              const float* __restrict__ bhh, const float* __restrict__ Wfc,
              const float* __restrict__ bfc, float* __restrict__ out,
              unsigned short* __restrict__ hb, unsigned* __restrict__ cnt,
              float* __restrict__ party)
{
    __shared__ int s_grp, s_ut, s_fast;
    __shared__ float gsp[4 * 4 * 16 * 20];  // 20 KB cross-wave partial-C

    const int tid = threadIdx.x;
    // cnt layout (uints, 16 KB zeroed): done at grp*64 ([0,512), 256B apart);
    // claim[8] at 512; bar1 at 544; pat at 1024+grp*64 (uint4);
    // pdone at 1536+grp*64; pflag 2048+grp*32; v_ok 2304+grp*32;
    // v_tot 2560+grp*32
    unsigned* claim = cnt + 512;
    unsigned* bar1  = cnt + 544;

    if (tid == 0) {
        unsigned xcc;
        asm volatile("s_getreg_b32 %0, hwreg(HW_REG_XCC_ID)" : "=s"(xcc));
        xcc &= 7u;
        const unsigned slot = add_agent(claim + xcc, 1u);
        asm volatile("s_waitcnt vmcnt(0)" ::: "memory");
        add_agent(bar1, 1u);
        while (ld_agent(bar1) < 256u) __builtin_amdgcn_s_sleep(1);
        bool pure = true;
        for (int g2 = 0; g2 < 8; ++g2) pure &= (ld_agent(claim + g2) == (unsigned)NBLK);

        int fast = 0, grp, ut;
        if (pure) {
            grp = (int)xcc; ut = (int)slot;
            // ---- probe the exact FAST mechanisms; waits are MALL+terminating
            unsigned* pat   = cnt + 1024 + grp * 64;
            unsigned* pdone = cnt + 1536 + grp * 64;
            unsigned* pflag = cnt + 2048 + grp * 32;
            unsigned* v_ok  = cnt + 2304 + grp * 32;
            unsigned* v_tot = cnt + 2560 + grp * 32;
            if (ut == 0) {
                uint4 m = make_uint4(0xC0FFEE42u, 0x5EED5EEDu, 0xA110C8EDu, 0xB16B00B5u);
                *(uint4*)pat = m;           // plain write-through store (h path)
                l2_signal_add(pdone, 5u);   // asm TCC atomic (signal path)
                asm volatile("s_waitcnt vmcnt(0)" ::: "memory");
                st_agent(pflag, 1u);
            }
            while (ld_agent(pflag) == 0u) __builtin_amdgcn_s_sleep(1);
            const uint4 d     = ld_sc0_probe(pat);   // data-read path (cold L1)
            const unsigned dv = l2_poll_rmw(pdone);  // poll path (TCC RMW)
            const unsigned ok = (d.x == 0xC0FFEE42u && d.y == 0x5EED5EEDu &&
                                 d.z == 0xA110C8EDu && d.w == 0xB16B00B5u &&
                                 dv == 5u) ? 1u : 0u;
            add_agent(v_ok, ok);
            asm volatile("s_waitcnt vmcnt(0)" ::: "memory");
            add_agent(v_tot, 1u);
            while (ld_agent(v_tot) < (unsigned)NBLK) __builtin_amdgcn_s_sleep(1);
            fast = (ld_agent(v_ok) == (unsigned)NBLK) ? 1 : 0;
        } else {
            grp = (int)(blockIdx.x >> 5); ut = (int)(blockIdx.x & 31);
        }
        s_grp = grp; s_ut = ut; s_fast = fast;
    }
    __syncthreads();
    const int grp = s_grp, ut = s_ut;
    unsigned* done = cnt + grp * 64;

    if (s_fast) run_loop<true >(x, Whh, Wih, bih, bhh, Wfc, bfc, out, hb, done, party, grp, ut, gsp);
    else        run_loop<false>(x, Whh, Wih, bih, bhh, Wfc, bfc, out, hb, done, party, grp, ut, gsp);
}

// y[b][t] = sum_ut part[g][ut][b&7][t] + bfc
__global__ __launch_bounds__(256)
void yred(const float* __restrict__ party, const float* __restrict__ bfc,
          float* __restrict__ out)
{
    const int i = blockIdx.x * 256 + threadIdx.x;  // over 64*2048
    const int b = i >> 11, t = i & 2047;
    const int g = b >> 3, lb = b & 7;
    const float* p = party + ((g * NBLK) * GB + lb) * TT + t;
    float s = bfc[0];
#pragma unroll 8
    for (int ut = 0; ut < NBLK; ++ut) s += p[ut * GB * TT];
    out[Y_OFF + b * TT + t] = s;
}

extern "C" void kernel_launch(void* const* d_in, const int* in_sizes, int n_in,
                              void* d_out, int out_size, void* d_ws, size_t ws_size,
                              hipStream_t stream) {
    const float* x   = (const float*)d_in[0];
    const float* Wih = (const float*)d_in[1];
    const float* Whh = (const float*)d_in[2];
    const float* bih = (const float*)d_in[3];
    const float* bhh = (const float*)d_in[4];
    const float* Wfc = (const float*)d_in[5];
    const float* bfc = (const float*)d_in[6];
    float* out = (float*)d_out;

    unsigned*       cnt = (unsigned*)d_ws;
    unsigned short* hb  = (unsigned short*)((char*)d_ws + RING_OFF);
    const bool use_part = ws_size >= (size_t)PART_OFF + PART_BYTES;
    float* party = use_part ? (float*)((char*)d_ws + PART_OFF) : nullptr;

    // zero counters/claims/probe + h ring (slot0 = h0 = 0); party is fully
    // overwritten before yred reads it.
    hipMemsetAsync(d_ws, 0, RING_OFF + 8 * 2 * DEPTH * PLANE * sizeof(unsigned short), stream);
    hipMemsetAsync(d_out, 0, BB * TT * sizeof(float), stream);  // fallback atomic target

    lstm_xcd<<<dim3(256), dim3(256), 0, stream>>>(
        x, Wih, Whh, bih, bhh, Wfc, bfc, out, hb, cnt, party);
    if (use_part)
        yred<<<dim3(BB * TT / 256), dim3(256), 0, stream>>>(party, bfc, out);
}